// Round 5
// baseline (336.049 us; speedup 1.0000x reference)
//
#include <hip/hip_runtime.h>
#include <hip/hip_bf16.h>

#define N_NODES 50000
#define N_EDGES 1600000
#define IN_F 256
#define OUT_C 256   // OUT_F * NHEAD
#define NHEAD 4
#define HEAD_F 64
#define LRELU_ALPHA 0.2f

#define SCAN_BS 512
#define SCAN_NB ((N_NODES + SCAN_BS - 1) / SCAN_BS)   // 98

typedef __attribute__((ext_vector_type(8))) _Float16 f16x8;
typedef __attribute__((ext_vector_type(4))) _Float16 f16x4;
typedef __attribute__((ext_vector_type(4))) float f32x4;

// ---------------- W pre-convert: f32 [K][N] -> chunked f16 hi/lo ----------------
__global__ __launch_bounds__(256) void k_convw(const float* __restrict__ Wm,
                                               _Float16* __restrict__ Wh,
                                               _Float16* __restrict__ Wl) {
    int t = blockIdx.x * 256 + threadIdx.x;   // 65536 = 256*256
    int k = t >> 8, n = t & 255;
    float f = Wm[t];                           // t == k*256+n
    _Float16 hi = (_Float16)f;
    _Float16 lo = (_Float16)(f - (float)hi);
    int idx = ((k >> 3) * 256 + n) * 8 + (k & 7);
    Wh[idx] = hi;
    Wl[idx] = lo;
}

// ---------------- GEMM: h16 = f16(x @ W), MFMA 16x16x32_f16, 3-term split ----------------
// fused epilogue: al[n,h] / ar[n,h] per-head dots from the f32 accumulator.
#define BM 64
#define BK 32
__global__ __launch_bounds__(256) void k_gemm(const float* __restrict__ x,
                                              const _Float16* __restrict__ Wh,
                                              const _Float16* __restrict__ Wl,
                                              const float* __restrict__ a_l,
                                              const float* __restrict__ a_r,
                                              _Float16* __restrict__ h16,
                                              float* __restrict__ al_out,
                                              float* __restrict__ ar_out) {
    __shared__ _Float16 Ah[4 * 64 * 8], Alo[4 * 64 * 8];
    __shared__ _Float16 Bh[4 * 256 * 8], Bl[4 * 256 * 8];
    __shared__ float s_al[256], s_ar[256];
    const int t = threadIdx.x;
    const int w = t >> 6;
    const int l = t & 63;
    const int row0 = blockIdx.x * BM;

    s_al[t] = a_l[t];
    s_ar[t] = a_r[t];

    f32x4 acc[16];
#pragma unroll
    for (int c = 0; c < 16; ++c) acc[c] = (f32x4)(0.f);

    const int kk_r = l >> 4;
    const int li   = l & 15;

    for (int ks = 0; ks < 8; ++ks) {
        const int k0 = ks * BK;
        __syncthreads();
        // ---- stage A: thread t -> (kk = t&3, row = t>>2); read 8 f32, split hi/lo
        {
            int kk = t & 3, row = t >> 2;
            int grow = row0 + row;
            float4 v0 = make_float4(0.f, 0.f, 0.f, 0.f);
            float4 v1 = make_float4(0.f, 0.f, 0.f, 0.f);
            if (grow < N_NODES) {
                const float* src = &x[(size_t)grow * IN_F + k0 + kk * 8];
                v0 = *(const float4*)src;
                v1 = *(const float4*)(src + 4);
            }
            float f[8] = {v0.x, v0.y, v0.z, v0.w, v1.x, v1.y, v1.z, v1.w};
            f16x8 vh, vl;
#pragma unroll
            for (int j = 0; j < 8; ++j) {
                _Float16 hi = (_Float16)f[j];
                vh[j] = hi;
                vl[j] = (_Float16)(f[j] - (float)hi);
            }
            int off = (kk * 64 + row) * 8;
            *(f16x8*)&Ah[off]  = vh;
            *(f16x8*)&Alo[off] = vl;
        }
        // ---- stage B: straight copies (global contiguous, LDS linear)
        {
            const size_t tb = (size_t)(k0 >> 3) * 256 * 8;
#pragma unroll
            for (int s = 0; s < 4; ++s) {
                int q = s * 256 + t;
                *(f16x8*)&Bh[q * 8] = *(const f16x8*)&Wh[tb + (size_t)q * 8];
                *(f16x8*)&Bl[q * 8] = *(const f16x8*)&Wl[tb + (size_t)q * 8];
            }
        }
        __syncthreads();
        f16x8 ah = *(f16x8*)&Ah[(kk_r * 64 + w * 16 + li) * 8];
        f16x8 al = *(f16x8*)&Alo[(kk_r * 64 + w * 16 + li) * 8];
#pragma unroll
        for (int c = 0; c < 16; ++c) {
            f16x8 bh = *(f16x8*)&Bh[(kk_r * 256 + c * 16 + li) * 8];
            f16x8 bl = *(f16x8*)&Bl[(kk_r * 256 + c * 16 + li) * 8];
            acc[c] = __builtin_amdgcn_mfma_f32_16x16x32_f16(ah, bh, acc[c], 0, 0, 0);
            acc[c] = __builtin_amdgcn_mfma_f32_16x16x32_f16(ah, bl, acc[c], 0, 0, 0);
            acc[c] = __builtin_amdgcn_mfma_f32_16x16x32_f16(al, bh, acc[c], 0, 0, 0);
        }
    }

    // ---- epilogue: C layout row=(l>>4)*4+j, col=c*16+li ----
    const int rbase = row0 + w * 16 + ((l >> 4) << 2);
#pragma unroll
    for (int c = 0; c < 16; ++c) {
#pragma unroll
        for (int j = 0; j < 4; ++j) {
            int row = rbase + j;
            if (row < N_NODES)
                h16[(size_t)row * OUT_C + c * 16 + li] = (_Float16)acc[c][j];
        }
    }
    // fused al/ar: column c*16+li belongs to head c>>2 (compile-time per c).
    float plh[4][4], prh[4][4];   // [head][j]
#pragma unroll
    for (int hd = 0; hd < 4; ++hd)
#pragma unroll
        for (int j = 0; j < 4; ++j) { plh[hd][j] = 0.f; prh[hd][j] = 0.f; }
#pragma unroll
    for (int c = 0; c < 16; ++c) {
        float av = s_al[c * 16 + li];
        float bv = s_ar[c * 16 + li];
#pragma unroll
        for (int j = 0; j < 4; ++j) {
            float v = acc[c][j];
            plh[c >> 2][j] += av * v;
            prh[c >> 2][j] += bv * v;
        }
    }
#pragma unroll
    for (int hd = 0; hd < 4; ++hd)
#pragma unroll
        for (int j = 0; j < 4; ++j)
#pragma unroll
            for (int s = 1; s <= 8; s <<= 1) {
                plh[hd][j] += __shfl_xor(plh[hd][j], s);
                prh[hd][j] += __shfl_xor(prh[hd][j], s);
            }
    if (li == 0) {
#pragma unroll
        for (int j = 0; j < 4; ++j) {
            int row = rbase + j;
            if (row < N_NODES) {
#pragma unroll
                for (int hd = 0; hd < 4; ++hd) {
                    al_out[row * NHEAD + hd] = plh[hd][j];
                    ar_out[row * NHEAD + hd] = prh[hd][j];
                }
            }
        }
    }
}

// ---------------- degree histogram ----------------
__global__ void k_deg(const int* __restrict__ ei, int* __restrict__ deg) {
    int e = blockIdx.x * blockDim.x + threadIdx.x;
    if (e < N_EDGES) atomicAdd(&deg[ei[e]], 1);
}

// ---------------- 3-kernel exclusive scan over deg ----------------
__global__ __launch_bounds__(SCAN_BS) void k_scan1(const int* __restrict__ deg,
                                                   int* __restrict__ incl,
                                                   int* __restrict__ bsums) {
    __shared__ int sm[SCAN_BS];
    const int tid = threadIdx.x;
    const int i = blockIdx.x * SCAN_BS + tid;
    int v = (i < N_NODES) ? deg[i] : 0;
    sm[tid] = v;
    __syncthreads();
    for (int off = 1; off < SCAN_BS; off <<= 1) {
        int add = (tid >= off) ? sm[tid - off] : 0;
        __syncthreads();
        sm[tid] += add;
        __syncthreads();
    }
    if (i < N_NODES) incl[i] = sm[tid];
    if (tid == SCAN_BS - 1) bsums[blockIdx.x] = sm[tid];
}

__global__ __launch_bounds__(128) void k_scan2(const int* __restrict__ bsums,
                                               int* __restrict__ boffs) {
    __shared__ int sm[128];
    const int tid = threadIdx.x;
    int v = (tid < SCAN_NB) ? bsums[tid] : 0;
    sm[tid] = v;
    __syncthreads();
    for (int off = 1; off < 128; off <<= 1) {
        int add = (tid >= off) ? sm[tid - off] : 0;
        __syncthreads();
        sm[tid] += add;
        __syncthreads();
    }
    if (tid < SCAN_NB) boffs[tid] = sm[tid] - v;   // exclusive
}

__global__ void k_scan3(int* __restrict__ offs, const int* __restrict__ deg,
                        const int* __restrict__ boffs) {
    int i = blockIdx.x * blockDim.x + threadIdx.x;
    if (i < N_NODES) offs[i] = offs[i] - deg[i] + boffs[i >> 9];  // 512 = 1<<9
}

// ---------------- CSR scatter ----------------
__global__ void k_scatter(const int* __restrict__ ei, const int* __restrict__ offs,
                          int* __restrict__ cursor, int* __restrict__ csr_col) {
    int e = blockIdx.x * blockDim.x + threadIdx.x;
    if (e < N_EDGES) {
        int r = ei[e];
        int c = ei[N_EDGES + e];
        int pos = offs[r] + atomicAdd(&cursor[r], 1);
        csr_col[pos] = c;
    }
}

// ---------------- per-row segment softmax + SpMM: ONE WAVE PER ROW, no barriers ----
// Block = 4 waves = 4 independent rows. Lane l owns features 4l..4l+3 (head l>>4).
// Per 64-edge chunk: lane i computes edge i's 4 weights -> wave-private LDS;
// then all 64 lanes sweep edges: 8B f16x4 gather + 4 v_fma_mix each.
__global__ __launch_bounds__(256) void k_agg(const int* __restrict__ csr_col,
                                             const int* __restrict__ offs,
                                             const int* __restrict__ deg,
                                             const float* __restrict__ al,
                                             const float* __restrict__ ar,
                                             const _Float16* __restrict__ h16,
                                             float* __restrict__ out) {
    __shared__ float s_w[4][64][4];   // [wave][edge][head] -> read hits 4 adjacent banks
    __shared__ int   s_c[4][64];
    const int t = threadIdx.x;
    const int w = t >> 6;
    const int l = t & 63;
    const int r = blockIdx.x * 4 + w;     // 50000/4 = 12500 exact
    const int hd = l >> 4;
    const int start = offs[r];
    const int dg = deg[r];

    const float4 alv = *(const float4*)&al[r * NHEAD];
    const float4* __restrict__ ar4 = (const float4*)ar;
    const f16x4* __restrict__ hb = (const f16x4*)h16;

    float a0 = 0.f, a1 = 0.f, a2 = 0.f, a3 = 0.f;
    float4 ps = make_float4(0.f, 0.f, 0.f, 0.f);

    for (int c0 = 0; c0 < dg; c0 += 64) {
        const int n = min(64, dg - c0);
        if (l < n) {
            int c = csr_col[start + c0 + l];
            s_c[w][l] = c;
            float4 arv = ar4[c];
            float e0 = alv.x + arv.x; e0 = (e0 >= 0.f) ? e0 : LRELU_ALPHA * e0;
            float e1 = alv.y + arv.y; e1 = (e1 >= 0.f) ? e1 : LRELU_ALPHA * e1;
            float e2 = alv.z + arv.z; e2 = (e2 >= 0.f) ? e2 : LRELU_ALPHA * e2;
            float e3 = alv.w + arv.w; e3 = (e3 >= 0.f) ? e3 : LRELU_ALPHA * e3;
            float4 wv;
            wv.x = __expf(fminf(e0, 80.f));
            wv.y = __expf(fminf(e1, 80.f));
            wv.z = __expf(fminf(e2, 80.f));
            wv.w = __expf(fminf(e3, 80.f));
            *(float4*)&s_w[w][l][0] = wv;
            ps.x += wv.x; ps.y += wv.y; ps.z += wv.z; ps.w += wv.w;
        }
        // wave-internal LDS write->read: compiler's lgkmcnt suffices, no barrier.
#pragma unroll 4
        for (int i = 0; i < n; ++i) {
            int c = s_c[w][i];                       // LDS broadcast
            float wt = s_w[w][i][hd];                // LDS broadcast (4 banks)
            f16x4 hv = hb[(unsigned)((c << 6) | l)]; // 8B coalesced gather
            a0 += (float)hv[0] * wt;
            a1 += (float)hv[1] * wt;
            a2 += (float)hv[2] * wt;
            a3 += (float)hv[3] * wt;
        }
    }

    // wave-reduce denominator (all heads), then select this lane's head
#pragma unroll
    for (int s = 1; s <= 32; s <<= 1) {
        ps.x += __shfl_xor(ps.x, s);
        ps.y += __shfl_xor(ps.y, s);
        ps.z += __shfl_xor(ps.z, s);
        ps.w += __shfl_xor(ps.w, s);
    }
    float den = (hd == 0) ? ps.x : (hd == 1) ? ps.y : (hd == 2) ? ps.z : ps.w;
    float inv = (den > 0.f) ? 1.f / den : 0.f;
    float4 o = make_float4(a0 * inv, a1 * inv, a2 * inv, a3 * inv);
    ((float4*)out)[(r << 6) | l] = o;
}

extern "C" void kernel_launch(void* const* d_in, const int* in_sizes, int n_in,
                              void* d_out, int out_size, void* d_ws, size_t ws_size,
                              hipStream_t stream) {
    const float* x   = (const float*)d_in[0];
    const int*   ei  = (const int*)d_in[1];
    const float* Wm  = (const float*)d_in[2];
    const float* a_l = (const float*)d_in[3];
    const float* a_r = (const float*)d_in[4];
    float* out = (float*)d_out;

    _Float16* h16 = (_Float16*)d_ws;                              // N*256 f16
    _Float16* Wh  = h16 + (size_t)N_NODES * OUT_C;                // 64K f16
    _Float16* Wl  = Wh + 256 * 256;                               // 64K f16
    float* al  = (float*)(Wl + 256 * 256);                        // N*4
    float* ar  = al + (size_t)N_NODES * NHEAD;                    // N*4
    int* deg    = (int*)(ar + (size_t)N_NODES * NHEAD);           // N
    int* cursor = deg + N_NODES;                                  // N
    int* offs   = cursor + N_NODES;                               // N
    int* bsums  = offs + N_NODES;                                 // 128
    int* boffs  = bsums + 128;                                    // 128
    int* csr_col = boffs + 128;                                   // E

    hipMemsetAsync(deg, 0, 2 * N_NODES * sizeof(int), stream);    // deg + cursor

    k_convw<<<256, 256, 0, stream>>>(Wm, Wh, Wl);
    k_gemm<<<(N_NODES + BM - 1) / BM, 256, 0, stream>>>(x, Wh, Wl, a_l, a_r, h16, al, ar);
    k_deg<<<(N_EDGES + 255) / 256, 256, 0, stream>>>(ei, deg);
    k_scan1<<<SCAN_NB, SCAN_BS, 0, stream>>>(deg, offs, bsums);
    k_scan2<<<1, 128, 0, stream>>>(bsums, boffs);
    k_scan3<<<(N_NODES + 255) / 256, 256, 0, stream>>>(offs, deg, boffs);
    k_scatter<<<(N_EDGES + 255) / 256, 256, 0, stream>>>(ei, offs, cursor, csr_col);
    k_agg<<<N_NODES / 4, 256, 0, stream>>>(csr_col, offs, deg, al, ar, h16, out);
}

// Round 6
// 310.478 us; speedup vs baseline: 1.0824x; 1.0824x over previous
//
#include <hip/hip_runtime.h>
#include <hip/hip_bf16.h>

#define N_NODES 50000
#define N_EDGES 1600000
#define IN_F 256
#define OUT_C 256   // OUT_F * NHEAD
#define NHEAD 4
#define HEAD_F 64
#define LRELU_ALPHA 0.2f

#define SCAN_BS 512
#define SCAN_NB ((N_NODES + SCAN_BS - 1) / SCAN_BS)   // 98

typedef __attribute__((ext_vector_type(8))) _Float16 f16x8;
typedef __attribute__((ext_vector_type(4))) float f32x4;

// ---------------- prep: W f32 -> chunked f16  +  degree histogram ----------------
// blocks [0,256): convert W (65536 elems). blocks [256, 256+6250): edge histogram.
__global__ __launch_bounds__(256) void k_prep(const float* __restrict__ Wm,
                                              _Float16* __restrict__ Wh,
                                              const int* __restrict__ ei,
                                              int* __restrict__ deg) {
    const int b = blockIdx.x;
    if (b < 256) {
        int t = b * 256 + threadIdx.x;     // t == k*256+n
        int k = t >> 8, n = t & 255;
        Wh[((k >> 3) * 256 + n) * 8 + (k & 7)] = (_Float16)Wm[t];
    } else {
        int e = (b - 256) * 256 + threadIdx.x;
        if (e < N_EDGES) atomicAdd(&deg[ei[e]], 1);
    }
}

// ---------------- GEMM: h16 = f16(x @ W), MFMA 16x16x32_f16 ----------------
// fused epilogue: al[n,h] / ar[n,h] per-head dots from the f32 accumulator.
#define BM 64
#define BK 32
__global__ __launch_bounds__(256) void k_gemm(const float* __restrict__ x,
                                              const _Float16* __restrict__ Wh,
                                              const float* __restrict__ a_l,
                                              const float* __restrict__ a_r,
                                              _Float16* __restrict__ h16,
                                              float* __restrict__ al_out,
                                              float* __restrict__ ar_out) {
    __shared__ _Float16 Ah[4 * 64 * 8];
    __shared__ _Float16 Bh[4 * 256 * 8];
    __shared__ float s_al[256], s_ar[256];
    const int t = threadIdx.x;
    const int w = t >> 6;
    const int l = t & 63;
    const int row0 = blockIdx.x * BM;

    s_al[t] = a_l[t];
    s_ar[t] = a_r[t];

    f32x4 acc[16];
#pragma unroll
    for (int c = 0; c < 16; ++c) acc[c] = (f32x4)(0.f);

    const int kk_r = l >> 4;
    const int li   = l & 15;

    for (int ks = 0; ks < 8; ++ks) {
        const int k0 = ks * BK;
        __syncthreads();
        // ---- stage A: thread t -> (kk = t&3, row = t>>2); read 8 f32 -> f16
        {
            int kk = t & 3, row = t >> 2;
            int grow = row0 + row;
            float4 v0 = make_float4(0.f, 0.f, 0.f, 0.f);
            float4 v1 = make_float4(0.f, 0.f, 0.f, 0.f);
            if (grow < N_NODES) {
                const float* src = &x[(size_t)grow * IN_F + k0 + kk * 8];
                v0 = *(const float4*)src;
                v1 = *(const float4*)(src + 4);
            }
            float f[8] = {v0.x, v0.y, v0.z, v0.w, v1.x, v1.y, v1.z, v1.w};
            f16x8 vh;
#pragma unroll
            for (int j = 0; j < 8; ++j) vh[j] = (_Float16)f[j];
            *(f16x8*)&Ah[(kk * 64 + row) * 8] = vh;
        }
        // ---- stage B: straight copy (global contiguous, LDS linear)
        {
            const size_t tb = (size_t)(k0 >> 3) * 256 * 8;
#pragma unroll
            for (int s = 0; s < 4; ++s) {
                int q = s * 256 + t;
                *(f16x8*)&Bh[q * 8] = *(const f16x8*)&Wh[tb + (size_t)q * 8];
            }
        }
        __syncthreads();
        f16x8 ah = *(f16x8*)&Ah[(kk_r * 64 + w * 16 + li) * 8];
#pragma unroll
        for (int c = 0; c < 16; ++c) {
            f16x8 bh = *(f16x8*)&Bh[(kk_r * 256 + c * 16 + li) * 8];
            acc[c] = __builtin_amdgcn_mfma_f32_16x16x32_f16(ah, bh, acc[c], 0, 0, 0);
        }
    }

    // ---- epilogue: C layout row=(l>>4)*4+j, col=c*16+li ----
    const int rbase = row0 + w * 16 + ((l >> 4) << 2);
#pragma unroll
    for (int c = 0; c < 16; ++c) {
#pragma unroll
        for (int j = 0; j < 4; ++j) {
            int row = rbase + j;
            if (row < N_NODES)
                h16[(size_t)row * OUT_C + c * 16 + li] = (_Float16)acc[c][j];
        }
    }
    // fused al/ar: column c*16+li belongs to head c>>2 (compile-time per c).
    float plh[4][4], prh[4][4];   // [head][j]
#pragma unroll
    for (int hd = 0; hd < 4; ++hd)
#pragma unroll
        for (int j = 0; j < 4; ++j) { plh[hd][j] = 0.f; prh[hd][j] = 0.f; }
#pragma unroll
    for (int c = 0; c < 16; ++c) {
        float av = s_al[c * 16 + li];
        float bv = s_ar[c * 16 + li];
#pragma unroll
        for (int j = 0; j < 4; ++j) {
            float v = acc[c][j];
            plh[c >> 2][j] += av * v;
            prh[c >> 2][j] += bv * v;
        }
    }
#pragma unroll
    for (int hd = 0; hd < 4; ++hd)
#pragma unroll
        for (int j = 0; j < 4; ++j)
#pragma unroll
            for (int s = 1; s <= 8; s <<= 1) {
                plh[hd][j] += __shfl_xor(plh[hd][j], s);
                prh[hd][j] += __shfl_xor(prh[hd][j], s);
            }
    if (li == 0) {
#pragma unroll
        for (int j = 0; j < 4; ++j) {
            int row = rbase + j;
            if (row < N_NODES) {
#pragma unroll
                for (int hd = 0; hd < 4; ++hd) {
                    al_out[row * NHEAD + hd] = plh[hd][j];
                    ar_out[row * NHEAD + hd] = prh[hd][j];
                }
            }
        }
    }
}

// ---------------- 3-kernel exclusive scan over deg ----------------
__global__ __launch_bounds__(SCAN_BS) void k_scan1(const int* __restrict__ deg,
                                                   int* __restrict__ incl,
                                                   int* __restrict__ bsums) {
    __shared__ int sm[SCAN_BS];
    const int tid = threadIdx.x;
    const int i = blockIdx.x * SCAN_BS + tid;
    int v = (i < N_NODES) ? deg[i] : 0;
    sm[tid] = v;
    __syncthreads();
    for (int off = 1; off < SCAN_BS; off <<= 1) {
        int add = (tid >= off) ? sm[tid - off] : 0;
        __syncthreads();
        sm[tid] += add;
        __syncthreads();
    }
    if (i < N_NODES) incl[i] = sm[tid];
    if (tid == SCAN_BS - 1) bsums[blockIdx.x] = sm[tid];
}

__global__ __launch_bounds__(128) void k_scan2(const int* __restrict__ bsums,
                                               int* __restrict__ boffs) {
    __shared__ int sm[128];
    const int tid = threadIdx.x;
    int v = (tid < SCAN_NB) ? bsums[tid] : 0;
    sm[tid] = v;
    __syncthreads();
    for (int off = 1; off < 128; off <<= 1) {
        int add = (tid >= off) ? sm[tid - off] : 0;
        __syncthreads();
        sm[tid] += add;
        __syncthreads();
    }
    if (tid < SCAN_NB) boffs[tid] = sm[tid] - v;   // exclusive
}

__global__ void k_scan3(int* __restrict__ offs, const int* __restrict__ deg,
                        const int* __restrict__ boffs) {
    int i = blockIdx.x * blockDim.x + threadIdx.x;
    if (i < N_NODES) offs[i] = offs[i] - deg[i] + boffs[i >> 9];  // 512 = 1<<9
}

// ---------------- CSR scatter ----------------
__global__ void k_scatter(const int* __restrict__ ei, const int* __restrict__ offs,
                          int* __restrict__ cursor, int* __restrict__ csr_col) {
    int e = blockIdx.x * blockDim.x + threadIdx.x;
    if (e < N_EDGES) {
        int r = ei[e];
        int c = ei[N_EDGES + e];
        int pos = offs[r] + atomicAdd(&cursor[r], 1);
        csr_col[pos] = c;
    }
}

// ---------------- per-row segment softmax + SpMM: ONE WAVE PER ROW ----------------
// Lane l: edge slot l>>5, feature block j=l&31 (features 8j..8j+7, head j>>3).
// Per iteration a wave consumes 2 edges: one 16B f16x8 gather + 8 v_fma_mix per lane.
__global__ __launch_bounds__(256) void k_agg(const int* __restrict__ csr_col,
                                             const int* __restrict__ offs,
                                             const int* __restrict__ deg,
                                             const float* __restrict__ al,
                                             const float* __restrict__ ar,
                                             const _Float16* __restrict__ h16,
                                             float* __restrict__ out) {
    __shared__ float s_w[4][64][4];   // [wave][edge][head]
    __shared__ int   s_c[4][64];
    const int t = threadIdx.x;
    const int w = t >> 6;
    const int l = t & 63;
    const int r = blockIdx.x * 4 + w;     // 50000/4 = 12500 exact
    const int eslot = l >> 5;
    const int j = l & 31;
    const int hd = j >> 3;
    const int start = offs[r];
    const int dg = deg[r];

    const float4 alv = *(const float4*)&al[r * NHEAD];
    const float4* __restrict__ ar4 = (const float4*)ar;
    const f16x8* __restrict__ h8 = (const f16x8*)h16;

    float acc[8];
#pragma unroll
    for (int k = 0; k < 8; ++k) acc[k] = 0.f;
    float4 ps = make_float4(0.f, 0.f, 0.f, 0.f);

    for (int c0 = 0; c0 < dg; c0 += 64) {
        const int n = min(64, dg - c0);
        if (l < n) {
            int c = csr_col[start + c0 + l];
            s_c[w][l] = c;
            float4 arv = ar4[c];
            float e0 = alv.x + arv.x; e0 = (e0 >= 0.f) ? e0 : LRELU_ALPHA * e0;
            float e1 = alv.y + arv.y; e1 = (e1 >= 0.f) ? e1 : LRELU_ALPHA * e1;
            float e2 = alv.z + arv.z; e2 = (e2 >= 0.f) ? e2 : LRELU_ALPHA * e2;
            float e3 = alv.w + arv.w; e3 = (e3 >= 0.f) ? e3 : LRELU_ALPHA * e3;
            float4 wv;
            wv.x = __expf(fminf(e0, 80.f));
            wv.y = __expf(fminf(e1, 80.f));
            wv.z = __expf(fminf(e2, 80.f));
            wv.w = __expf(fminf(e3, 80.f));
            *(float4*)&s_w[w][l][0] = wv;
            ps.x += wv.x; ps.y += wv.y; ps.z += wv.z; ps.w += wv.w;
        }
        // wave-internal LDS write->read: lgkmcnt dependency suffices, no barrier.
        const int np = (n + 1) >> 1;
#pragma unroll 8
        for (int p = 0; p < np; ++p) {
            int i0 = 2 * p + eslot;
            bool v = (i0 < n);
            int c = v ? s_c[w][i0] : s_c[w][0];
            float wt = v ? s_w[w][i0][hd] : 0.f;
            f16x8 hv = h8[(unsigned)((c << 5) | j)];   // 16B coalesced gather
#pragma unroll
            for (int k = 0; k < 8; ++k)
                acc[k] += (float)hv[k] * wt;           // v_fma_mix_f32
        }
    }

    // combine the two edge slots
#pragma unroll
    for (int k = 0; k < 8; ++k) acc[k] += __shfl_xor(acc[k], 32);

    // wave-reduce denominator (all heads), select this lane's head
#pragma unroll
    for (int s = 1; s <= 32; s <<= 1) {
        ps.x += __shfl_xor(ps.x, s);
        ps.y += __shfl_xor(ps.y, s);
        ps.z += __shfl_xor(ps.z, s);
        ps.w += __shfl_xor(ps.w, s);
    }
    float den = (hd == 0) ? ps.x : (hd == 1) ? ps.y : (hd == 2) ? ps.z : ps.w;
    float inv = (den > 0.f) ? 1.f / den : 0.f;
    if (l < 32) {
        float4 o0 = make_float4(acc[0] * inv, acc[1] * inv, acc[2] * inv, acc[3] * inv);
        float4 o1 = make_float4(acc[4] * inv, acc[5] * inv, acc[6] * inv, acc[7] * inv);
        float4* op = (float4*)&out[((size_t)r << 8) + j * 8];
        op[0] = o0;
        op[1] = o1;
    }
}

extern "C" void kernel_launch(void* const* d_in, const int* in_sizes, int n_in,
                              void* d_out, int out_size, void* d_ws, size_t ws_size,
                              hipStream_t stream) {
    const float* x   = (const float*)d_in[0];
    const int*   ei  = (const int*)d_in[1];
    const float* Wm  = (const float*)d_in[2];
    const float* a_l = (const float*)d_in[3];
    const float* a_r = (const float*)d_in[4];
    float* out = (float*)d_out;

    _Float16* h16 = (_Float16*)d_ws;                              // N*256 f16
    _Float16* Wh  = h16 + (size_t)N_NODES * OUT_C;                // 64K f16
    float* al  = (float*)(Wh + 256 * 256);                        // N*4
    float* ar  = al + (size_t)N_NODES * NHEAD;                    // N*4
    int* deg    = (int*)(ar + (size_t)N_NODES * NHEAD);           // N
    int* cursor = deg + N_NODES;                                  // N
    int* offs   = cursor + N_NODES;                               // N
    int* bsums  = offs + N_NODES;                                 // 128
    int* boffs  = bsums + 128;                                    // 128
    int* csr_col = boffs + 128;                                   // E

    hipMemsetAsync(deg, 0, 2 * N_NODES * sizeof(int), stream);    // deg + cursor

    k_prep<<<256 + (N_EDGES + 255) / 256, 256, 0, stream>>>(Wm, Wh, ei, deg);
    k_gemm<<<(N_NODES + BM - 1) / BM, 256, 0, stream>>>(x, Wh, a_l, a_r, h16, al, ar);
    k_scan1<<<SCAN_NB, SCAN_BS, 0, stream>>>(deg, offs, bsums);
    k_scan2<<<1, 128, 0, stream>>>(bsums, boffs);
    k_scan3<<<(N_NODES + 255) / 256, 256, 0, stream>>>(offs, deg, boffs);
    k_scatter<<<(N_EDGES + 255) / 256, 256, 0, stream>>>(ei, offs, cursor, csr_col);
    k_agg<<<N_NODES / 4, 256, 0, stream>>>(csr_col, offs, deg, al, ar, h16, out);
}